// Round 3
// baseline (2865.216 us; speedup 1.0000x reference)
//
#include <hip/hip_runtime.h>
#include <hip/hip_bf16.h>
#include <float.h>

// PatchCore NN-distance: nn_dists[q] = min_m ||query_q - memory_m||, plus max over q.
// Rows are L2-normalized => d2 = 2 - 2*(q.m). R3: MX-scaled fp8 (e4m3) MFMA GEMM,
// 32x32x64 f8f6f4 with E8M0 scales 2^-6 compensating a x64 input pre-scale.
// global_load_lds(16B) staging with XOR-swizzled 16B chunks (bank-conflict-free reads).

#define QN 4096
#define MN 100000
#define MP 100096             // MN padded to multiple of 128 (pad rows zeroed)
#define DN 1536               // elements; also bytes per row in fp8
#define BKF 64                // fp8 bytes per K-step
#define NKF (DN / BKF)        // 24
#define SCALE_M6 0x79797979   // E8M0 byte 121 = 2^-6 (per operand; product 2^-12 undoes 64*64)

typedef __attribute__((ext_vector_type(8)))  int   int8v;
typedef __attribute__((ext_vector_type(4)))  int   int4v;
typedef __attribute__((ext_vector_type(16))) float float16v;
typedef __attribute__((ext_vector_type(8)))  short short8;
typedef __attribute__((ext_vector_type(4)))  short short4v;
typedef __attribute__((ext_vector_type(4)))  float float4v;
typedef __attribute__((address_space(1))) const unsigned g_u32;
typedef __attribute__((address_space(3))) unsigned l_u32;

__device__ __forceinline__ short f2bf(float f) {            // fp32 -> bf16 RNE (fallback path)
    unsigned u = __float_as_uint(f);
    u += 0x7FFFu + ((u >> 16) & 1u);
    return (short)(u >> 16);
}
__device__ __forceinline__ unsigned encf(float f) {         // monotone float->uint
    unsigned u = __float_as_uint(f);
    return (u & 0x80000000u) ? ~u : (u | 0x80000000u);
}
__device__ __forceinline__ float decf(unsigned e) {
    unsigned u = (e & 0x80000000u) ? (e & 0x7FFFFFFFu) : ~e;
    return __uint_as_float(u);
}
__device__ __forceinline__ void gload_lds16(const void* g, void* l) {
    __builtin_amdgcn_global_load_lds((g_u32*)g, (l_u32*)l, 16, 0, 0);
}

__global__ void init_min(unsigned* __restrict__ dminEnc) {
    int i = blockIdx.x * blockDim.x + threadIdx.x;
    if (i < QN) dminEnc[i] = 0xFF7FFFFFu;  // encf(FLT_MAX)
}

// fp32 -> fp8 e4m3 (HW cvt, RNE+sat), values pre-scaled by 64; zero-fill [n_valid, n_total)
__global__ void cvt_fp8(const float* __restrict__ src, unsigned char* __restrict__ dst,
                        long n_valid, long n_total) {
    long i = ((long)blockIdx.x * blockDim.x + threadIdx.x) * 8;
    if (i >= n_total) return;
    if (i + 8 <= n_valid) {
        float4 v0 = *(const float4*)(src + i);
        float4 v1 = *(const float4*)(src + i + 4);
        int p0 = __builtin_amdgcn_cvt_pk_fp8_f32(v0.x * 64.f, v0.y * 64.f, 0, 0);
        p0     = __builtin_amdgcn_cvt_pk_fp8_f32(v0.z * 64.f, v0.w * 64.f, p0, 1);
        int p1 = __builtin_amdgcn_cvt_pk_fp8_f32(v1.x * 64.f, v1.y * 64.f, 0, 0);
        p1     = __builtin_amdgcn_cvt_pk_fp8_f32(v1.z * 64.f, v1.w * 64.f, p1, 1);
        int2 o = { p0, p1 };
        *(int2*)(dst + i) = o;
    } else {
        for (int j = 0; j < 8; ++j)
            if (i + j < n_total) {
                float f = (i + j < n_valid) ? src[i + j] * 64.f : 0.f;
                int p = __builtin_amdgcn_cvt_pk_fp8_f32(f, 0.f, 0, 0);
                dst[i + j] = (unsigned char)(p & 0xFF);
            }
    }
}

// ---------------- fast path: MX-fp8 GEMM, global_load_lds staging -----------------
// LDS layout per tile: row-major 64B rows; 16B chunk p at row r holds logical
// k-chunk (p ^ ((r>>1)&3)) -> ds_read_b128 phases of 8 lanes hit disjoint bank-quads.
__global__ __launch_bounds__(256)
void nn_gemm_fp8(const unsigned char* __restrict__ qF, const unsigned char* __restrict__ mF,
                 unsigned* __restrict__ dminEnc)
{
    __shared__ __align__(16) unsigned char As[128 * BKF];   // 8 KB
    __shared__ __align__(16) unsigned char Bs[128 * BKF];   // 8 KB
    __shared__ unsigned qmin[128];

    const int tid  = threadIdx.x;
    const int lane = tid & 63;
    const int wave = tid >> 6;
    const int wrow = wave >> 1;   // 64-row strip of queries
    const int wcol = wave & 1;    // 64-col strip of memory rows

    const int qb = blockIdx.x * 128;
    const int mb = blockIdx.y * 128;

    if (tid < 128) qmin[tid] = 0xFFFFFFFFu;

    // --- staging: per wave, 2 calls/matrix, each 16 rows x 64B. lane -> row (lane>>2),
    // physical chunk (lane&3); global source chunk = (lane&3) ^ ((lane>>3)&3) (swizzle).
    const int srow = wave * 32 + (lane >> 2);
    const int jb   = (((lane & 3) ^ ((lane >> 3) & 3))) * 16;   // swizzled global byte chunk
    const unsigned char* gA0 = qF + (size_t)(qb + srow) * DN + jb;
    const unsigned char* gA1 = gA0 + (size_t)16 * DN;
    const unsigned char* gB0 = mF + (size_t)(mb + srow) * DN + jb;
    const unsigned char* gB1 = gB0 + (size_t)16 * DN;
    unsigned char* lA0 = As + (wave * 32) * BKF;        // HW adds lane*16
    unsigned char* lA1 = As + (wave * 32 + 16) * BKF;
    unsigned char* lB0 = Bs + (wave * 32) * BKF;
    unsigned char* lB1 = Bs + (wave * 32 + 16) * BKF;

    // --- fragment read addressing (unswizzle): row r31 = lane&31, logical chunks
    // c0 = (lane>>5)*2, c0+1; physical = logical ^ ((r31>>1)&3).
    const int r31 = lane & 31;
    const int sw  = (r31 >> 1) & 3;
    const int c0  = (lane >> 5) * 2;
    const int po0 = (c0 ^ sw) * 16;          // byte offset of logical chunk c0
    const int po1 = ((c0 + 1) ^ sw) * 16;    // byte offset of logical chunk c0+1

    float16v acc[2][2];
#pragma unroll
    for (int mi = 0; mi < 2; ++mi)
#pragma unroll
        for (int ni = 0; ni < 2; ++ni)
#pragma unroll
            for (int e = 0; e < 16; ++e) acc[mi][ni][e] = 0.f;

    for (int kk = 0; kk < NKF; ++kk) {
        const size_t ko = (size_t)kk * BKF;
        gload_lds16(gA0 + ko, lA0);
        gload_lds16(gA1 + ko, lA1);
        gload_lds16(gB0 + ko, lB0);
        gload_lds16(gB1 + ko, lB1);
        __syncthreads();                      // drains vmcnt -> LDS valid

        int8v af[2], bf[2];
#pragma unroll
        for (int mi = 0; mi < 2; ++mi) {
            const int rb = (wrow * 64 + mi * 32 + r31) * BKF;
            int4v lo = *(const int4v*)&As[rb + po0];
            int4v hi = *(const int4v*)&As[rb + po1];
            af[mi][0] = lo[0]; af[mi][1] = lo[1]; af[mi][2] = lo[2]; af[mi][3] = lo[3];
            af[mi][4] = hi[0]; af[mi][5] = hi[1]; af[mi][6] = hi[2]; af[mi][7] = hi[3];
        }
#pragma unroll
        for (int ni = 0; ni < 2; ++ni) {
            const int rb = (wcol * 64 + ni * 32 + r31) * BKF;
            int4v lo = *(const int4v*)&Bs[rb + po0];
            int4v hi = *(const int4v*)&Bs[rb + po1];
            bf[ni][0] = lo[0]; bf[ni][1] = lo[1]; bf[ni][2] = lo[2]; bf[ni][3] = lo[3];
            bf[ni][4] = hi[0]; bf[ni][5] = hi[1]; bf[ni][6] = hi[2]; bf[ni][7] = hi[3];
        }

#pragma unroll
        for (int mi = 0; mi < 2; ++mi)
#pragma unroll
            for (int ni = 0; ni < 2; ++ni)
                acc[mi][ni] = __builtin_amdgcn_mfma_scale_f32_32x32x64_f8f6f4(
                    af[mi], bf[ni], acc[mi][ni],
                    0 /*A=e4m3*/, 0 /*B=e4m3*/,
                    0, SCALE_M6, 0, SCALE_M6);
        __syncthreads();                      // protect LDS before next stage
    }

    // epilogue: d2 = 2 - 2*s ; min over this block's 128 cols per query row.
    // C/D 32x32 layout: col = lane&31, row = (reg&3) + 8*(reg>>2) + 4*(lane>>5).
#pragma unroll
    for (int mi = 0; mi < 2; ++mi) {
#pragma unroll
        for (int r = 0; r < 16; ++r) {
            float v = FLT_MAX;
#pragma unroll
            for (int ni = 0; ni < 2; ++ni) {
                int gcol = mb + wcol * 64 + ni * 32 + r31;
                float d2 = fmaf(-2.0f, acc[mi][ni][r], 2.0f);
                v = fminf(v, (gcol < MN) ? d2 : FLT_MAX);
            }
            v = fminf(v, __shfl_xor(v, 1));
            v = fminf(v, __shfl_xor(v, 2));
            v = fminf(v, __shfl_xor(v, 4));
            v = fminf(v, __shfl_xor(v, 8));
            v = fminf(v, __shfl_xor(v, 16));
            if (r31 == 0) {
                int rloc = wrow * 64 + mi * 32 + (r & 3) + 8 * (r >> 2) + 4 * (lane >> 5);
                atomicMin(&qmin[rloc], encf(v));
            }
        }
    }
    __syncthreads();
    if (tid < 128) atomicMin(&dminEnc[qb + tid], qmin[tid]);
}

// ---------------- fallback path (fp32 inputs, bf16 MFMA, in-kernel cvt) -----------------
#define BK 32
#define NKIT (DN / BK)
#define LDSS 40
__global__ __launch_bounds__(256, 2)
void nn_gemm_f32(const float* __restrict__ query, const float* __restrict__ memory,
                 unsigned* __restrict__ dminEnc)
{
    __shared__ __align__(16) short As[128 * LDSS];
    __shared__ __align__(16) short Bs[128 * LDSS];
    __shared__ unsigned qmin[128];

    const int tid = threadIdx.x, lane = tid & 63, wave = tid >> 6;
    const int wrow = wave >> 1, wcol = wave & 1, quad = lane >> 4, l16 = lane & 15;
    const int qb = blockIdx.x * 128, mb = blockIdx.y * 128;
    if (tid < 128) qmin[tid] = 0xFFFFFFFFu;

    int rowS[4], c4S[4];
    const float *aPtr[4], *bPtr[4];
    bool bValid[4];
#pragma unroll
    for (int s = 0; s < 4; ++s) {
        int idx = s * 256 + tid, row = idx >> 3, c4 = idx & 7;
        rowS[s] = row; c4S[s] = c4;
        aPtr[s] = query + (size_t)(qb + row) * DN + c4 * 4;
        int gr = mb + row;
        bValid[s] = (gr < MN);
        bPtr[s] = memory + (size_t)(bValid[s] ? gr : 0) * DN + c4 * 4;
    }
    float4 aReg[4], bReg[4];
#pragma unroll
    for (int s = 0; s < 4; ++s) {
        aReg[s] = *(const float4*)(aPtr[s]);
        bReg[s] = bValid[s] ? *(const float4*)(bPtr[s]) : make_float4(0.f, 0.f, 0.f, 0.f);
    }
    float4v acc[4][4];
#pragma unroll
    for (int mi = 0; mi < 4; ++mi)
#pragma unroll
        for (int ni = 0; ni < 4; ++ni) acc[mi][ni] = (float4v){0.f, 0.f, 0.f, 0.f};

    for (int kk = 0; kk < NKIT; ++kk) {
#pragma unroll
        for (int s = 0; s < 4; ++s) {
            short4v pa = { f2bf(aReg[s].x), f2bf(aReg[s].y), f2bf(aReg[s].z), f2bf(aReg[s].w) };
            short4v pb = { f2bf(bReg[s].x), f2bf(bReg[s].y), f2bf(bReg[s].z), f2bf(bReg[s].w) };
            *(short4v*)&As[rowS[s] * LDSS + c4S[s] * 4] = pa;
            *(short4v*)&Bs[rowS[s] * LDSS + c4S[s] * 4] = pb;
        }
        __syncthreads();
        if (kk + 1 < NKIT) {
            const int ko = (kk + 1) * BK;
#pragma unroll
            for (int s = 0; s < 4; ++s) {
                aReg[s] = *(const float4*)(aPtr[s] + ko);
                bReg[s] = bValid[s] ? *(const float4*)(bPtr[s] + ko)
                                    : make_float4(0.f, 0.f, 0.f, 0.f);
            }
        }
        short8 af[4], bf[4];
#pragma unroll
        for (int mi = 0; mi < 4; ++mi)
            af[mi] = *(const short8*)&As[(wrow * 64 + mi * 16 + l16) * LDSS + quad * 8];
#pragma unroll
        for (int ni = 0; ni < 4; ++ni)
            bf[ni] = *(const short8*)&Bs[(wcol * 64 + ni * 16 + l16) * LDSS + quad * 8];
#pragma unroll
        for (int mi = 0; mi < 4; ++mi)
#pragma unroll
            for (int ni = 0; ni < 4; ++ni)
                acc[mi][ni] = __builtin_amdgcn_mfma_f32_16x16x32_bf16(
                    af[mi], bf[ni], acc[mi][ni], 0, 0, 0);
        __syncthreads();
    }
#pragma unroll
    for (int mi = 0; mi < 4; ++mi) {
#pragma unroll
        for (int r = 0; r < 4; ++r) {
            float v = FLT_MAX;
#pragma unroll
            for (int ni = 0; ni < 4; ++ni) {
                int gcol = mb + wcol * 64 + ni * 16 + l16;
                float d2 = fmaf(-2.0f, acc[mi][ni][r], 2.0f);
                v = fminf(v, (gcol < MN) ? d2 : FLT_MAX);
            }
            v = fminf(v, __shfl_xor(v, 1));
            v = fminf(v, __shfl_xor(v, 2));
            v = fminf(v, __shfl_xor(v, 4));
            v = fminf(v, __shfl_xor(v, 8));
            if (l16 == 0)
                atomicMin(&qmin[wrow * 64 + mi * 16 + quad * 4 + r], encf(v));
        }
    }
    __syncthreads();
    if (tid < 128) atomicMin(&dminEnc[qb + tid], qmin[tid]);
}

__global__ void finalize(const unsigned* __restrict__ dminEnc, float* __restrict__ out) {
    __shared__ float red[256];
    const int tid = threadIdx.x;
    float mx = 0.f;
    for (int i = tid; i < QN; i += 256) {
        float d2 = decf(dminEnc[i]);
        float d = sqrtf(fmaxf(d2, 0.f));
        out[i] = d;
        mx = fmaxf(mx, d);
    }
    red[tid] = mx;
    __syncthreads();
    for (int s = 128; s > 0; s >>= 1) {
        if (tid < s) red[tid] = fmaxf(red[tid], red[tid + s]);
        __syncthreads();
    }
    if (tid == 0) out[QN] = red[0];
}

extern "C" void kernel_launch(void* const* d_in, const int* in_sizes, int n_in,
                              void* d_out, int out_size, void* d_ws, size_t ws_size,
                              hipStream_t stream)
{
    const float* query  = (const float*)d_in[0];
    const float* memory = (const float*)d_in[1];
    float* out = (float*)d_out;

    const size_t memF_bytes = (size_t)MP * DN;          // padded fp8 memory
    const size_t qF_bytes   = (size_t)QN * DN;
    const size_t need = memF_bytes + qF_bytes + (size_t)QN * 4;

    if (ws_size >= need) {
        unsigned char* mF = (unsigned char*)d_ws;
        unsigned char* qF = mF + memF_bytes;
        unsigned* dminEnc = (unsigned*)(qF + qF_bytes);

        hipLaunchKernelGGL(init_min, dim3((QN + 255) / 256), dim3(256), 0, stream, dminEnc);
        {
            long nv = (long)MN * DN, nt = (long)memF_bytes;
            int blocks = (int)((nt / 8 + 255) / 256);
            hipLaunchKernelGGL(cvt_fp8, dim3(blocks), dim3(256), 0, stream, memory, mF, nv, nt);
        }
        {
            long nv = (long)qF_bytes, nt = (long)qF_bytes;
            int blocks = (int)((nt / 8 + 255) / 256);
            hipLaunchKernelGGL(cvt_fp8, dim3(blocks), dim3(256), 0, stream, query, qF, nv, nt);
        }
        hipLaunchKernelGGL(nn_gemm_fp8, dim3(QN / 128, MP / 128), dim3(256), 0, stream,
                           qF, mF, dminEnc);
        hipLaunchKernelGGL(finalize, dim3(1), dim3(256), 0, stream, dminEnc, out);
    } else {
        unsigned* dminEnc = (unsigned*)d_ws;
        hipLaunchKernelGGL(init_min, dim3((QN + 255) / 256), dim3(256), 0, stream, dminEnc);
        hipLaunchKernelGGL(nn_gemm_f32, dim3(QN / 128, (MN + 127) / 128), dim3(256), 0, stream,
                           query, memory, dminEnc);
        hipLaunchKernelGGL(finalize, dim3(1), dim3(256), 0, stream, dminEnc, out);
    }
}